// Round 20
// baseline (220.485 us; speedup 1.0000x reference)
//
#include <hip/hip_runtime.h>
#include <hip/hip_fp16.h>

// Problem constants (fixed by the reference setup)
#define N_NODES 50000
#define IN_DIM 256
#define OUT_DIM 128
#define NNZ 800000          // nnz for feat, adj1, adj2 each
#define SCAN_N (3 * N_NODES)        // 150000 row pointers (feat | adj1 | adj2)
#define TOTAL_NNZ (3 * NNZ)         // spack sized for 3 segs; seg0 unused

// Sub-buckets: 98-row ranges, 511 of them (511*98 = 50078 >= 50000).
// Expected entries/bucket = 2.4M*98/50000 = 4704, sigma ~68.
// SUBCAP 6144 = mean + 21 sigma (populations HW-validated rounds 2..19).
#define NSB 511
#define SUBW 98
#define SUBCAP 6144

// superbucket: 512 threads x 2 edges (int2/float2 paired loads) = 1024
// edges/block -> 3072 entries staged in 24 KB.
#define EB 1024
#define SB_GRID ((NNZ + EB - 1) / EB)   // 782; last block nE=256 (even)

// adj phase: ONE fused dispatch (measured ~62 us rounds 15-19,
// request/latency floor; keep).
#define ADJ_SL 4
#define ADJ_RC ((N_NODES + 63) / 64)  // 782 row-chunks of 64 rows

// Native clang vector types.
typedef float vf4 __attribute__((ext_vector_type(4)));

// Packed entry: [col:16 | fp16(val):16].  adj cols < 50000 < 65536, feat cols < 256.
static __device__ __forceinline__ unsigned pack_cv(int c, float v) {
    return ((unsigned)c << 16) | (unsigned)__half_as_ushort(__float2half(v));
}
static __device__ __forceinline__ int   upk_c(unsigned pk) { return (int)(pk >> 16); }
static __device__ __forceinline__ float upk_v(unsigned pk) {
    return __half2float(__ushort_as_half((unsigned short)(pk & 0xffffu)));
}
static __device__ __forceinline__ float h2f(unsigned short h) {
    return __half2float(__ushort_as_half(h));
}
static __device__ __forceinline__ unsigned pk2h(float x, float y) {
    return (unsigned)__half_as_ushort(__float2half(x))
         | ((unsigned)__half_as_ushort(__float2half(y)) << 16);
}

// -----------------------------------------------------------------------------
// wprep: interleave W1|W2 into ONE fp16 table (cache-resident, 128 KB).
// Wc[c*32 + l] (uint4) = { w1[c, 4l..4l+3], w2[c, 4l..4l+3] } as 8 halves.
// -----------------------------------------------------------------------------
__global__ void wprep_kernel(const float* __restrict__ W1,
                             const float* __restrict__ W2,
                             uint4* __restrict__ Wc) {
    int idx = blockIdx.x * 256 + threadIdx.x;   // 8192 = 256 rows * 32 lanes
    const float4* w1 = (const float4*)W1;
    const float4* w2 = (const float4*)W2;
    float4 a = w1[idx];
    float4 b = w2[idx];
    uint4 o;
    o.x = pk2h(a.x, a.y);
    o.y = pk2h(a.z, a.w);
    o.z = pk2h(b.x, b.y);
    o.w = pk2h(b.z, b.w);
    Wc[idx] = o;
}

// -----------------------------------------------------------------------------
// A (superbucket_kernel): read every edge ONCE via PAIRED int2/float2 loads
// (9 x 8B loads/thread, was 18 x 4B), LDS-group 3072 entries by final 98-row
// bucket (row/98, 511 buckets), append ~6-entry chunks to per-bucket storage.
// Entry = u64 [sb:16|key:16|pack:32], key = seg*98 + row%98 in [0,294).
// Write-out: combo[] = gb - offE (1 LDS read/entry, was 2) + nt u64 stores
// (single-consumer stream; avoids L2 RFO on partial-line runs).
// -----------------------------------------------------------------------------
__global__ __launch_bounds__(512) void superbucket_kernel(
        const int* __restrict__ fr, const int* __restrict__ fc,
        const float* __restrict__ fv,
        const int* __restrict__ a1r, const int* __restrict__ a1c,
        const float* __restrict__ a1v,
        const int* __restrict__ a2r, const int* __restrict__ a2c,
        const float* __restrict__ a2v,
        int* __restrict__ subcur,
        unsigned long long* __restrict__ gbuf) {
    __shared__ unsigned long long stage[3 * EB];   // 24 KB
    __shared__ int c512[512];                      // +2 KB
    __shared__ int offE[512];                      // +2 KB
    __shared__ int combo[512];                     // +2 KB (gb - offE)
    __shared__ int wsum[8];
    int t = threadIdx.x;
    c512[t] = 0;
    __syncthreads();
    int base = blockIdx.x * EB;
    int nE = NNZ - base; if (nE > EB) nE = EB;     // 1024 or 256: always even
    int tot = 3 * nE;

    unsigned long long ent[6]; int sbA[6]; int loc[6];
    bool act = (2 * t) < nE;
    if (act) {
        int p2 = (base >> 1) + t;                  // pair index (8B-aligned)
        int2   fR  = ((const int2*)fr)[p2];
        int2   fC  = ((const int2*)fc)[p2];
        float2 fV  = ((const float2*)fv)[p2];
        int2   bR  = ((const int2*)a1r)[p2];
        int2   bC  = ((const int2*)a1c)[p2];
        float2 bV  = ((const float2*)a1v)[p2];
        int2   cR  = ((const int2*)a2r)[p2];
        int2   cC  = ((const int2*)a2c)[p2];
        float2 cV  = ((const float2*)a2v)[p2];
        int   rr[6] = { fR.x, bR.x, cR.x, fR.y, bR.y, cR.y };
        int   cc[6] = { fC.x, bC.x, cC.x, fC.y, bC.y, cC.y };
        float vv[6] = { fV.x, bV.x, cV.x, fV.y, bV.y, cV.y };
        const int sg[6] = { 0, 1, 2, 0, 1, 2 };
#pragma unroll
        for (int k = 0; k < 6; ++k) {
            int s0 = rr[k] / SUBW;
            ent[k] = ((unsigned long long)s0 << 48)
                   | ((unsigned long long)(sg[k] * SUBW + rr[k] - s0 * SUBW) << 32)
                   | pack_cv(cc[k], vv[k]);
            sbA[k] = s0;
            loc[k] = atomicAdd(&c512[s0], 1);
        }
    } else {
#pragma unroll
        for (int k = 0; k < 6; ++k) sbA[k] = -1;
    }
    __syncthreads();
    // Wave-level inclusive scan over the 512 bucket counts (2 barriers).
    int lane = t & 63, wid = t >> 6;
    int v = c512[t];
    int incl = v;
#pragma unroll
    for (int d = 1; d < 64; d <<= 1) {
        int u = __shfl_up(incl, d, 64);
        if (lane >= d) incl += u;
    }
    if (lane == 63) wsum[wid] = incl;
    __syncthreads();
    int wpre = 0;
#pragma unroll
    for (int w = 0; w < 8; ++w) wpre += (w < wid) ? wsum[w] : 0;
    int excl = incl + wpre - v;
    offE[t] = excl;
    int gbv = (v > 0) ? atomicAdd(&subcur[t], v) : 0;
    combo[t] = gbv - excl;
    __syncthreads();
#pragma unroll
    for (int k = 0; k < 6; ++k) {
        if (sbA[k] >= 0) stage[offE[sbA[k]] + loc[k]] = ent[k];
    }
    __syncthreads();
    // Write-out: ~6-entry contiguous chunks per bucket; 1 LDS read + nt store.
    for (int i = t; i < tot; i += 512) {
        unsigned long long e = stage[i];
        int sb = (int)(e >> 48);
        __builtin_nontemporal_store(
            e, &gbuf[(size_t)sb * SUBCAP + combo[sb] + i]);
    }
}

// -----------------------------------------------------------------------------
// B (sort_write_feat_kernel): per-bucket LDS counting sort + FUSED feat phase.
//   - writes adj segs 1/2 to spack (contiguous, self-allocated via cur3) and
//     emits starts+rowlen;
//   - 16 x 32-lane row-groups compute xw rows straight from LDS (broadcast
//     reads; Wc cache-resident). Wave-level scan; single u64 load per entry.
// (Byte-identical to round-19's passing version.)
// -----------------------------------------------------------------------------
__global__ __launch_bounds__(512) void sort_write_feat_kernel(
        const unsigned long long* __restrict__ gbuf,
        const int* __restrict__ subcur,
        int* __restrict__ cur3,
        int* __restrict__ starts,
        int* __restrict__ rowlen,
        unsigned* __restrict__ spack,
        const uint4* __restrict__ Wc,
        ushort4* __restrict__ xw1s,
        ushort4* __restrict__ xw2s) {
    int sb = blockIdx.x;                 // 0..510
    int n = subcur[sb];
    __shared__ int h[512];
    __shared__ int e[512];
    __shared__ int cur[512];
    __shared__ int gbs[3];               // per-segment global (within-seg) base
    __shared__ int wsum[8];
    __shared__ unsigned sorted[SUBCAP];  // 24 KB
    int t = threadIdx.x;
    h[t] = 0;
    __syncthreads();
    size_t base = (size_t)sb * SUBCAP;
    unsigned pk[12]; short ky[12];
#pragma unroll
    for (int k = 0; k < 12; ++k) {           // SUBCAP = 12*512 exactly
        int i = t + k * 512;
        if (i < n) {
            unsigned long long ent = gbuf[base + i];
            pk[k] = (unsigned)ent;
            ky[k] = (short)((ent >> 32) & 0xffffu);  // key in [0,294)
            atomicAdd(&h[ky[k]], 1);
        } else ky[k] = -1;
    }
    __syncthreads();
    // Wave-level inclusive scan over h[512] (2 barriers).
    int lane = t & 63, wid = t >> 6;
    int v = h[t];
    int incl = v;
#pragma unroll
    for (int d = 1; d < 64; d <<= 1) {
        int u = __shfl_up(incl, d, 64);
        if (lane >= d) incl += u;
    }
    if (lane == 63) wsum[wid] = incl;
    __syncthreads();
    int wpre = 0;
#pragma unroll
    for (int w = 0; w < 8; ++w) wpre += (w < wid) ? wsum[w] : 0;
    int excl = incl + wpre - v;
    e[t] = excl;
    cur[t] = excl;
    __syncthreads();
    // Reserve per-segment global ranges from the scanned boundaries.
    if (t < 3) {
        int lo = (t == 0) ? 0 : ((t == 1) ? e[SUBW] : e[2 * SUBW]);
        int hi = (t == 0) ? e[SUBW] : ((t == 1) ? e[2 * SUBW] : n);
        gbs[t] = atomicAdd(&cur3[t], hi - lo);
    }
    // LDS scatter (concurrent with the t<3 reservations; disjoint memory).
#pragma unroll
    for (int k = 0; k < 12; ++k) {
        if (ky[k] >= 0) {
            int pos = atomicAdd(&cur[ky[k]], 1);
            sorted[pos] = pk[k];
        }
    }
    __syncthreads();
    int s1 = e[SUBW];                    // local start of adj1 entries
    int s2 = e[2 * SUBW];                // local start of adj2 entries
    // Emit row pointers + lengths (98 rows x 3 segments; seg0 harmless/unused).
    if (t < 3 * SUBW) {
        int s = t / SUBW, d = t - s * SUBW;
        int r = sb * SUBW + d;
        if (r < N_NODES) {
            int segb = (s == 0) ? 0 : ((s == 1) ? s1 : s2);
            int gr = s * N_NODES + r;
            starts[gr] = s * NNZ + gbs[s] + (e[t] - segb);
            rowlen[gr] = h[t];
        }
    }
    // Coalesced contiguous entry write-out: adj segments 1/2 ONLY.
#pragma unroll
    for (int k = 0; k < 12; ++k) {
        int i = t + k * 512;
        if (i >= s1 && i < n) {
            int sg = (i < s2) ? 1 : 2;
            int segb = (i < s2) ? s1 : s2;
            spack[sg * NNZ + gbs[sg] + (i - segb)] = sorted[i];
        }
    }
    // FUSED feat phase: 16 row-groups of 32 lanes; row keys 0..97 are seg0.
    int grp  = t >> 5;                   // 0..15
    int ln   = t & 31;
    for (int rowIdx = grp; rowIdx < SUBW; rowIdx += 16) {
        int r = sb * SUBW + rowIdx;
        if (r >= N_NODES) continue;      // uniform per group
        int cnt = h[rowIdx];
        int bs  = e[rowIdx];
        float4 a1 = make_float4(0.f, 0.f, 0.f, 0.f);
        float4 a2 = make_float4(0.f, 0.f, 0.f, 0.f);
        int j = 0;
        for (; j + 3 < cnt; j += 4) {
            unsigned p0 = sorted[bs + j];        // LDS broadcast (no conflict)
            unsigned p1 = sorted[bs + j + 1];
            unsigned p2 = sorted[bs + j + 2];
            unsigned p3 = sorted[bs + j + 3];
            uint4 w0 = Wc[upk_c(p0) * 32 + ln];
            uint4 w1 = Wc[upk_c(p1) * 32 + ln];
            uint4 w2 = Wc[upk_c(p2) * 32 + ln];
            uint4 w3 = Wc[upk_c(p3) * 32 + ln];
            float v0 = upk_v(p0), v1 = upk_v(p1), v2 = upk_v(p2), v3 = upk_v(p3);
            a1.x += v0 * h2f((unsigned short)(w0.x & 0xffffu));
            a1.y += v0 * h2f((unsigned short)(w0.x >> 16));
            a1.z += v0 * h2f((unsigned short)(w0.y & 0xffffu));
            a1.w += v0 * h2f((unsigned short)(w0.y >> 16));
            a2.x += v0 * h2f((unsigned short)(w0.z & 0xffffu));
            a2.y += v0 * h2f((unsigned short)(w0.z >> 16));
            a2.z += v0 * h2f((unsigned short)(w0.w & 0xffffu));
            a2.w += v0 * h2f((unsigned short)(w0.w >> 16));
            a1.x += v1 * h2f((unsigned short)(w1.x & 0xffffu));
            a1.y += v1 * h2f((unsigned short)(w1.x >> 16));
            a1.z += v1 * h2f((unsigned short)(w1.y & 0xffffu));
            a1.w += v1 * h2f((unsigned short)(w1.y >> 16));
            a2.x += v1 * h2f((unsigned short)(w1.z & 0xffffu));
            a2.y += v1 * h2f((unsigned short)(w1.z >> 16));
            a2.z += v1 * h2f((unsigned short)(w1.w & 0xffffu));
            a2.w += v1 * h2f((unsigned short)(w1.w >> 16));
            a1.x += v2 * h2f((unsigned short)(w2.x & 0xffffu));
            a1.y += v2 * h2f((unsigned short)(w2.x >> 16));
            a1.z += v2 * h2f((unsigned short)(w2.y & 0xffffu));
            a1.w += v2 * h2f((unsigned short)(w2.y >> 16));
            a2.x += v2 * h2f((unsigned short)(w2.z & 0xffffu));
            a2.y += v2 * h2f((unsigned short)(w2.z >> 16));
            a2.z += v2 * h2f((unsigned short)(w2.w & 0xffffu));
            a2.w += v2 * h2f((unsigned short)(w2.w >> 16));
            a1.x += v3 * h2f((unsigned short)(w3.x & 0xffffu));
            a1.y += v3 * h2f((unsigned short)(w3.x >> 16));
            a1.z += v3 * h2f((unsigned short)(w3.y & 0xffffu));
            a1.w += v3 * h2f((unsigned short)(w3.y >> 16));
            a2.x += v3 * h2f((unsigned short)(w3.z & 0xffffu));
            a2.y += v3 * h2f((unsigned short)(w3.z >> 16));
            a2.z += v3 * h2f((unsigned short)(w3.w & 0xffffu));
            a2.w += v3 * h2f((unsigned short)(w3.w >> 16));
        }
        for (; j < cnt; ++j) {
            unsigned p = sorted[bs + j];
            float v5 = upk_v(p);
            uint4 w = Wc[upk_c(p) * 32 + ln];
            a1.x += v5 * h2f((unsigned short)(w.x & 0xffffu));
            a1.y += v5 * h2f((unsigned short)(w.x >> 16));
            a1.z += v5 * h2f((unsigned short)(w.y & 0xffffu));
            a1.w += v5 * h2f((unsigned short)(w.y >> 16));
            a2.x += v5 * h2f((unsigned short)(w.z & 0xffffu));
            a2.y += v5 * h2f((unsigned short)(w.z >> 16));
            a2.z += v5 * h2f((unsigned short)(w.w & 0xffffu));
            a2.w += v5 * h2f((unsigned short)(w.w >> 16));
        }
        ushort4 q1, q2;
        q1.x = __half_as_ushort(__float2half(a1.x));
        q1.y = __half_as_ushort(__float2half(a1.y));
        q1.z = __half_as_ushort(__float2half(a1.z));
        q1.w = __half_as_ushort(__float2half(a1.w));
        q2.x = __half_as_ushort(__float2half(a2.x));
        q2.y = __half_as_ushort(__float2half(a2.y));
        q2.z = __half_as_ushort(__float2half(a2.z));
        q2.w = __half_as_ushort(__float2half(a2.w));
        // 32-dim-slice layout: xw[s][r][d32], lane's slice = ln>>3.
        size_t idx = (size_t)(ln >> 3) * (N_NODES * 8) + (size_t)r * 8 + (ln & 7);
        xw1s[idx] = q1;
        xw2s[idx] = q2;
    }
}

// -----------------------------------------------------------------------------
// Phase 2, FUSED (measured ~62 us rounds 15-19; request/latency floor, keep):
//   out[r, 32s:32s+32] = relu( sum_adj1 v*xw1[s][c][:] + sum_adj2 v*xw2[s][c][:] )
// -----------------------------------------------------------------------------
__global__ __launch_bounds__(512) void adj_pass_fused(
        const int* __restrict__ starts,
        const int* __restrict__ rowlen,
        const unsigned* __restrict__ spack,
        const ushort4* __restrict__ xw1s,
        const ushort4* __restrict__ xw2s,
        vf4* __restrict__ out) {
    int s  = blockIdx.x & (ADJ_SL - 1);
    int rc = blockIdx.x >> 2;
    int g  = threadIdx.x >> 3;          // 64 row-groups per block
    int q  = threadIdx.x & 7;
    int r  = rc * 64 + g;
    bool valid = (r < N_NODES);
    vf4 acc = {0.f, 0.f, 0.f, 0.f};

#pragma unroll
    for (int rel = 0; rel < 2; ++rel) {
        const ushort4* __restrict__ sl =
            ((rel == 0) ? xw1s : xw2s) + (size_t)s * (N_NODES * 8);
        int st = 0, en = 0;
        if (valid) {
            st = starts[(1 + rel) * N_NODES + r];
            en = st + rowlen[(1 + rel) * N_NODES + r];
        }
        for (int base = st; base < en; base += 16) {
            int m = en - base;
            unsigned pk0 = (q < m)     ? spack[base + q]     : 0u;
            unsigned pk1 = (8 + q < m) ? spack[base + 8 + q] : 0u;
            {
                unsigned pp[8]; ushort4 xx[8];
#pragma unroll
                for (int k = 0; k < 8; ++k) pp[k] = __shfl(pk0, k, 8);
#pragma unroll
                for (int k = 0; k < 8; ++k) xx[k] = sl[upk_c(pp[k]) * 8 + q];
#pragma unroll
                for (int k = 0; k < 8; ++k) {
                    float v = upk_v(pp[k]);
                    acc.x += v * h2f(xx[k].x); acc.y += v * h2f(xx[k].y);
                    acc.z += v * h2f(xx[k].z); acc.w += v * h2f(xx[k].w);
                }
            }
            if (m <= 8) continue;
            {
                unsigned pp[8]; ushort4 xx[8];
#pragma unroll
                for (int k = 0; k < 8; ++k) pp[k] = __shfl(pk1, k, 8);
#pragma unroll
                for (int k = 0; k < 8; ++k) xx[k] = sl[upk_c(pp[k]) * 8 + q];
#pragma unroll
                for (int k = 0; k < 8; ++k) {
                    float v = upk_v(pp[k]);
                    acc.x += v * h2f(xx[k].x); acc.y += v * h2f(xx[k].y);
                    acc.z += v * h2f(xx[k].z); acc.w += v * h2f(xx[k].w);
                }
            }
        }
    }
    if (valid) {
        vf4 res;
        res.x = fmaxf(acc.x, 0.f);
        res.y = fmaxf(acc.y, 0.f);
        res.z = fmaxf(acc.z, 0.f);
        res.w = fmaxf(acc.w, 0.f);
        __builtin_nontemporal_store(res, &out[(size_t)r * 32 + s * 8 + q]);
    }
}

extern "C" void kernel_launch(void* const* d_in, const int* in_sizes, int n_in,
                              void* d_out, int out_size, void* d_ws, size_t ws_size,
                              hipStream_t stream) {
    const int*   feat_row  = (const int*)  d_in[0];
    const int*   feat_col  = (const int*)  d_in[1];
    const float* feat_vals = (const float*)d_in[2];
    const int*   adj1_row  = (const int*)  d_in[3];
    const int*   adj1_col  = (const int*)  d_in[4];
    const float* adj1_vals = (const float*)d_in[5];
    const int*   adj2_row  = (const int*)  d_in[6];
    const int*   adj2_col  = (const int*)  d_in[7];
    const float* adj2_vals = (const float*)d_in[8];
    const float* W1        = (const float*)d_in[9];
    const float* W2        = (const float*)d_in[10];

    // Workspace layout (~62 MB, no aliasing).
    char* ws = (char*)d_ws;
    unsigned* spack = (unsigned*)ws;            ws += (size_t)TOTAL_NNZ * 4;          // 9.6 MB
    int*      starts= (int*)ws;                 ws += (size_t)SCAN_N * 4;             // 600 KB
    int*      rowlen= (int*)ws;                 ws += (size_t)SCAN_N * 4;             // 600 KB
    int*      subcur= (int*)ws;                 ws += 512 * 4;                        // 511 used
    int*      cur3  = (int*)ws;                 ws += 16 * 4;                         // 3 used
    uint4*    Wc    = (uint4*)ws;               ws += (size_t)256 * 32 * 16;          // 128 KB
    unsigned long long* gbuf = (unsigned long long*)ws;
    ws += (size_t)NSB * SUBCAP * 8;                                                  // 25.1 MB
    ushort4*  xw1s  = (ushort4*)ws;             ws += (size_t)N_NODES * OUT_DIM * 2;  // 12.8 MB
    ushort4*  xw2s  = (ushort4*)ws;             ws += (size_t)N_NODES * OUT_DIM * 2;  // 12.8 MB

    // Zero cursors: subcur(512) + cur3(16), contiguous.
    (void)hipMemsetAsync(subcur, 0, (512 + 16) * sizeof(int), stream);

    // W prep: interleaved fp16 table.
    wprep_kernel<<<32, 256, 0, stream>>>(W1, W2, Wc);

    // A: single pass — read all 9 streams once (paired 8B loads), bucket into
    // 511 sub-buckets.
    superbucket_kernel<<<SB_GRID, 512, 0, stream>>>(
        feat_row, feat_col, feat_vals,
        adj1_row, adj1_col, adj1_vals,
        adj2_row, adj2_col, adj2_vals,
        subcur, gbuf);

    // B: sort + adj spack write + FUSED feat xw compute.
    sort_write_feat_kernel<<<NSB, 512, 0, stream>>>(
        gbuf, subcur, cur3, starts, rowlen, spack, Wc, xw1s, xw2s);

    // Phase 2: FUSED rel0+rel1, 32-dim slices.
    adj_pass_fused<<<ADJ_SL * ADJ_RC, 512, 0, stream>>>(
        starts, rowlen, spack, xw1s, xw2s, (vf4*)d_out);
}

// Round 21
// 212.540 us; speedup vs baseline: 1.0374x; 1.0374x over previous
//
#include <hip/hip_runtime.h>
#include <hip/hip_fp16.h>

// Problem constants (fixed by the reference setup)
#define N_NODES 50000
#define IN_DIM 256
#define OUT_DIM 128
#define NNZ 800000          // nnz for feat, adj1, adj2 each
#define SCAN_N (3 * N_NODES)        // 150000 row pointers (feat | adj1 | adj2)
#define TOTAL_NNZ (3 * NNZ)         // spack sized for 3 segs; seg0 unused

// Sub-buckets: 98-row ranges, 511 of them (511*98 = 50078 >= 50000).
// Expected entries/bucket = 2.4M*98/50000 = 4704, sigma ~68.
// SUBCAP 6144 = mean + 21 sigma (populations HW-validated rounds 2..20).
#define NSB 511
#define SUBW 98
#define SUBCAP 6144

// superbucket: 512 threads x 2 edges (int2/float2 paired loads) = 1024
// edges/block -> 3072 entries staged in 24 KB.
#define EB 1024
#define SB_GRID ((NNZ + EB - 1) / EB)   // 782; last block nE=256 (even)

// adj phase: ONE fused dispatch (measured ~62 us rounds 15-20,
// request/latency floor; keep).
#define ADJ_SL 4
#define ADJ_RC ((N_NODES + 63) / 64)  // 782 row-chunks of 64 rows

// Native clang vector types.
typedef float vf4 __attribute__((ext_vector_type(4)));

// Packed entry: [col:16 | fp16(val):16].  adj cols < 50000 < 65536, feat cols < 256.
static __device__ __forceinline__ unsigned pack_cv(int c, float v) {
    return ((unsigned)c << 16) | (unsigned)__half_as_ushort(__float2half(v));
}
static __device__ __forceinline__ int   upk_c(unsigned pk) { return (int)(pk >> 16); }
static __device__ __forceinline__ float upk_v(unsigned pk) {
    return __half2float(__ushort_as_half((unsigned short)(pk & 0xffffu)));
}
static __device__ __forceinline__ float h2f(unsigned short h) {
    return __half2float(__ushort_as_half(h));
}
static __device__ __forceinline__ unsigned pk2h(float x, float y) {
    return (unsigned)__half_as_ushort(__float2half(x))
         | ((unsigned)__half_as_ushort(__float2half(y)) << 16);
}

// -----------------------------------------------------------------------------
// wprep: interleave W1|W2 into ONE fp16 table (cache-resident, 128 KB).
// Wc[c*32 + l] (uint4) = { w1[c, 4l..4l+3], w2[c, 4l..4l+3] } as 8 halves.
// -----------------------------------------------------------------------------
__global__ void wprep_kernel(const float* __restrict__ W1,
                             const float* __restrict__ W2,
                             uint4* __restrict__ Wc) {
    int idx = blockIdx.x * 256 + threadIdx.x;   // 8192 = 256 rows * 32 lanes
    const float4* w1 = (const float4*)W1;
    const float4* w2 = (const float4*)W2;
    float4 a = w1[idx];
    float4 b = w2[idx];
    uint4 o;
    o.x = pk2h(a.x, a.y);
    o.y = pk2h(a.z, a.w);
    o.z = pk2h(b.x, b.y);
    o.w = pk2h(b.z, b.w);
    Wc[idx] = o;
}

// -----------------------------------------------------------------------------
// A (superbucket_kernel): read every edge ONCE via PAIRED int2/float2 loads
// (9 x 8B loads/thread), LDS-group 3072 entries by final 98-row bucket
// (row/98, 511 buckets), append ~6-entry chunks to per-bucket storage.
// Entry = u64 [sb:16|key:16|pack:32], key = seg*98 + row%98 in [0,294).
// Write-out: combo[] = gb - offE (1 LDS read/entry) + PLAIN u64 stores.
// ROUND-20 LESSON: nt stores on gbuf regressed +7.6 us — gbuf is consumed
// immediately by pass B, so L2-warmth is exactly what we want. Never nt
// data the next kernel reads.
// -----------------------------------------------------------------------------
__global__ __launch_bounds__(512) void superbucket_kernel(
        const int* __restrict__ fr, const int* __restrict__ fc,
        const float* __restrict__ fv,
        const int* __restrict__ a1r, const int* __restrict__ a1c,
        const float* __restrict__ a1v,
        const int* __restrict__ a2r, const int* __restrict__ a2c,
        const float* __restrict__ a2v,
        int* __restrict__ subcur,
        unsigned long long* __restrict__ gbuf) {
    __shared__ unsigned long long stage[3 * EB];   // 24 KB
    __shared__ int c512[512];                      // +2 KB
    __shared__ int offE[512];                      // +2 KB
    __shared__ int combo[512];                     // +2 KB (gb - offE)
    __shared__ int wsum[8];
    int t = threadIdx.x;
    c512[t] = 0;
    __syncthreads();
    int base = blockIdx.x * EB;
    int nE = NNZ - base; if (nE > EB) nE = EB;     // 1024 or 256: always even
    int tot = 3 * nE;

    unsigned long long ent[6]; int sbA[6]; int loc[6];
    bool act = (2 * t) < nE;
    if (act) {
        int p2 = (base >> 1) + t;                  // pair index (8B-aligned)
        int2   fR  = ((const int2*)fr)[p2];
        int2   fC  = ((const int2*)fc)[p2];
        float2 fV  = ((const float2*)fv)[p2];
        int2   bR  = ((const int2*)a1r)[p2];
        int2   bC  = ((const int2*)a1c)[p2];
        float2 bV  = ((const float2*)a1v)[p2];
        int2   cR  = ((const int2*)a2r)[p2];
        int2   cC  = ((const int2*)a2c)[p2];
        float2 cV  = ((const float2*)a2v)[p2];
        int   rr[6] = { fR.x, bR.x, cR.x, fR.y, bR.y, cR.y };
        int   cc[6] = { fC.x, bC.x, cC.x, fC.y, bC.y, cC.y };
        float vv[6] = { fV.x, bV.x, cV.x, fV.y, bV.y, cV.y };
        const int sg[6] = { 0, 1, 2, 0, 1, 2 };
#pragma unroll
        for (int k = 0; k < 6; ++k) {
            int s0 = rr[k] / SUBW;
            ent[k] = ((unsigned long long)s0 << 48)
                   | ((unsigned long long)(sg[k] * SUBW + rr[k] - s0 * SUBW) << 32)
                   | pack_cv(cc[k], vv[k]);
            sbA[k] = s0;
            loc[k] = atomicAdd(&c512[s0], 1);
        }
    } else {
#pragma unroll
        for (int k = 0; k < 6; ++k) sbA[k] = -1;
    }
    __syncthreads();
    // Wave-level inclusive scan over the 512 bucket counts (2 barriers).
    int lane = t & 63, wid = t >> 6;
    int v = c512[t];
    int incl = v;
#pragma unroll
    for (int d = 1; d < 64; d <<= 1) {
        int u = __shfl_up(incl, d, 64);
        if (lane >= d) incl += u;
    }
    if (lane == 63) wsum[wid] = incl;
    __syncthreads();
    int wpre = 0;
#pragma unroll
    for (int w = 0; w < 8; ++w) wpre += (w < wid) ? wsum[w] : 0;
    int excl = incl + wpre - v;
    offE[t] = excl;
    int gbv = (v > 0) ? atomicAdd(&subcur[t], v) : 0;
    combo[t] = gbv - excl;
    __syncthreads();
#pragma unroll
    for (int k = 0; k < 6; ++k) {
        if (sbA[k] >= 0) stage[offE[sbA[k]] + loc[k]] = ent[k];
    }
    __syncthreads();
    // Write-out: ~6-entry contiguous chunks per bucket; 1 LDS read, plain
    // store (keeps gbuf L2-warm for pass B).
    for (int i = t; i < tot; i += 512) {
        unsigned long long e = stage[i];
        int sb = (int)(e >> 48);
        gbuf[(size_t)sb * SUBCAP + combo[sb] + i] = e;
    }
}

// -----------------------------------------------------------------------------
// B (sort_write_feat_kernel): per-bucket LDS counting sort + FUSED feat phase.
//   - writes adj segs 1/2 to spack (contiguous, self-allocated via cur3) and
//     emits starts+rowlen;
//   - 16 x 32-lane row-groups compute xw rows straight from LDS (broadcast
//     reads; Wc cache-resident). Wave-level scan; single u64 load per entry.
// (Byte-identical to round-19's passing version.)
// -----------------------------------------------------------------------------
__global__ __launch_bounds__(512) void sort_write_feat_kernel(
        const unsigned long long* __restrict__ gbuf,
        const int* __restrict__ subcur,
        int* __restrict__ cur3,
        int* __restrict__ starts,
        int* __restrict__ rowlen,
        unsigned* __restrict__ spack,
        const uint4* __restrict__ Wc,
        ushort4* __restrict__ xw1s,
        ushort4* __restrict__ xw2s) {
    int sb = blockIdx.x;                 // 0..510
    int n = subcur[sb];
    __shared__ int h[512];
    __shared__ int e[512];
    __shared__ int cur[512];
    __shared__ int gbs[3];               // per-segment global (within-seg) base
    __shared__ int wsum[8];
    __shared__ unsigned sorted[SUBCAP];  // 24 KB
    int t = threadIdx.x;
    h[t] = 0;
    __syncthreads();
    size_t base = (size_t)sb * SUBCAP;
    unsigned pk[12]; short ky[12];
#pragma unroll
    for (int k = 0; k < 12; ++k) {           // SUBCAP = 12*512 exactly
        int i = t + k * 512;
        if (i < n) {
            unsigned long long ent = gbuf[base + i];
            pk[k] = (unsigned)ent;
            ky[k] = (short)((ent >> 32) & 0xffffu);  // key in [0,294)
            atomicAdd(&h[ky[k]], 1);
        } else ky[k] = -1;
    }
    __syncthreads();
    // Wave-level inclusive scan over h[512] (2 barriers).
    int lane = t & 63, wid = t >> 6;
    int v = h[t];
    int incl = v;
#pragma unroll
    for (int d = 1; d < 64; d <<= 1) {
        int u = __shfl_up(incl, d, 64);
        if (lane >= d) incl += u;
    }
    if (lane == 63) wsum[wid] = incl;
    __syncthreads();
    int wpre = 0;
#pragma unroll
    for (int w = 0; w < 8; ++w) wpre += (w < wid) ? wsum[w] : 0;
    int excl = incl + wpre - v;
    e[t] = excl;
    cur[t] = excl;
    __syncthreads();
    // Reserve per-segment global ranges from the scanned boundaries.
    if (t < 3) {
        int lo = (t == 0) ? 0 : ((t == 1) ? e[SUBW] : e[2 * SUBW]);
        int hi = (t == 0) ? e[SUBW] : ((t == 1) ? e[2 * SUBW] : n);
        gbs[t] = atomicAdd(&cur3[t], hi - lo);
    }
    // LDS scatter (concurrent with the t<3 reservations; disjoint memory).
#pragma unroll
    for (int k = 0; k < 12; ++k) {
        if (ky[k] >= 0) {
            int pos = atomicAdd(&cur[ky[k]], 1);
            sorted[pos] = pk[k];
        }
    }
    __syncthreads();
    int s1 = e[SUBW];                    // local start of adj1 entries
    int s2 = e[2 * SUBW];                // local start of adj2 entries
    // Emit row pointers + lengths (98 rows x 3 segments; seg0 harmless/unused).
    if (t < 3 * SUBW) {
        int s = t / SUBW, d = t - s * SUBW;
        int r = sb * SUBW + d;
        if (r < N_NODES) {
            int segb = (s == 0) ? 0 : ((s == 1) ? s1 : s2);
            int gr = s * N_NODES + r;
            starts[gr] = s * NNZ + gbs[s] + (e[t] - segb);
            rowlen[gr] = h[t];
        }
    }
    // Coalesced contiguous entry write-out: adj segments 1/2 ONLY.
#pragma unroll
    for (int k = 0; k < 12; ++k) {
        int i = t + k * 512;
        if (i >= s1 && i < n) {
            int sg = (i < s2) ? 1 : 2;
            int segb = (i < s2) ? s1 : s2;
            spack[sg * NNZ + gbs[sg] + (i - segb)] = sorted[i];
        }
    }
    // FUSED feat phase: 16 row-groups of 32 lanes; row keys 0..97 are seg0.
    int grp  = t >> 5;                   // 0..15
    int ln   = t & 31;
    for (int rowIdx = grp; rowIdx < SUBW; rowIdx += 16) {
        int r = sb * SUBW + rowIdx;
        if (r >= N_NODES) continue;      // uniform per group
        int cnt = h[rowIdx];
        int bs  = e[rowIdx];
        float4 a1 = make_float4(0.f, 0.f, 0.f, 0.f);
        float4 a2 = make_float4(0.f, 0.f, 0.f, 0.f);
        int j = 0;
        for (; j + 3 < cnt; j += 4) {
            unsigned p0 = sorted[bs + j];        // LDS broadcast (no conflict)
            unsigned p1 = sorted[bs + j + 1];
            unsigned p2 = sorted[bs + j + 2];
            unsigned p3 = sorted[bs + j + 3];
            uint4 w0 = Wc[upk_c(p0) * 32 + ln];
            uint4 w1 = Wc[upk_c(p1) * 32 + ln];
            uint4 w2 = Wc[upk_c(p2) * 32 + ln];
            uint4 w3 = Wc[upk_c(p3) * 32 + ln];
            float v0 = upk_v(p0), v1 = upk_v(p1), v2 = upk_v(p2), v3 = upk_v(p3);
            a1.x += v0 * h2f((unsigned short)(w0.x & 0xffffu));
            a1.y += v0 * h2f((unsigned short)(w0.x >> 16));
            a1.z += v0 * h2f((unsigned short)(w0.y & 0xffffu));
            a1.w += v0 * h2f((unsigned short)(w0.y >> 16));
            a2.x += v0 * h2f((unsigned short)(w0.z & 0xffffu));
            a2.y += v0 * h2f((unsigned short)(w0.z >> 16));
            a2.z += v0 * h2f((unsigned short)(w0.w & 0xffffu));
            a2.w += v0 * h2f((unsigned short)(w0.w >> 16));
            a1.x += v1 * h2f((unsigned short)(w1.x & 0xffffu));
            a1.y += v1 * h2f((unsigned short)(w1.x >> 16));
            a1.z += v1 * h2f((unsigned short)(w1.y & 0xffffu));
            a1.w += v1 * h2f((unsigned short)(w1.y >> 16));
            a2.x += v1 * h2f((unsigned short)(w1.z & 0xffffu));
            a2.y += v1 * h2f((unsigned short)(w1.z >> 16));
            a2.z += v1 * h2f((unsigned short)(w1.w & 0xffffu));
            a2.w += v1 * h2f((unsigned short)(w1.w >> 16));
            a1.x += v2 * h2f((unsigned short)(w2.x & 0xffffu));
            a1.y += v2 * h2f((unsigned short)(w2.x >> 16));
            a1.z += v2 * h2f((unsigned short)(w2.y & 0xffffu));
            a1.w += v2 * h2f((unsigned short)(w2.y >> 16));
            a2.x += v2 * h2f((unsigned short)(w2.z & 0xffffu));
            a2.y += v2 * h2f((unsigned short)(w2.z >> 16));
            a2.z += v2 * h2f((unsigned short)(w2.w & 0xffffu));
            a2.w += v2 * h2f((unsigned short)(w2.w >> 16));
            a1.x += v3 * h2f((unsigned short)(w3.x & 0xffffu));
            a1.y += v3 * h2f((unsigned short)(w3.x >> 16));
            a1.z += v3 * h2f((unsigned short)(w3.y & 0xffffu));
            a1.w += v3 * h2f((unsigned short)(w3.y >> 16));
            a2.x += v3 * h2f((unsigned short)(w3.z & 0xffffu));
            a2.y += v3 * h2f((unsigned short)(w3.z >> 16));
            a2.z += v3 * h2f((unsigned short)(w3.w & 0xffffu));
            a2.w += v3 * h2f((unsigned short)(w3.w >> 16));
        }
        for (; j < cnt; ++j) {
            unsigned p = sorted[bs + j];
            float v5 = upk_v(p);
            uint4 w = Wc[upk_c(p) * 32 + ln];
            a1.x += v5 * h2f((unsigned short)(w.x & 0xffffu));
            a1.y += v5 * h2f((unsigned short)(w.x >> 16));
            a1.z += v5 * h2f((unsigned short)(w.y & 0xffffu));
            a1.w += v5 * h2f((unsigned short)(w.y >> 16));
            a2.x += v5 * h2f((unsigned short)(w.z & 0xffffu));
            a2.y += v5 * h2f((unsigned short)(w.z >> 16));
            a2.z += v5 * h2f((unsigned short)(w.w & 0xffffu));
            a2.w += v5 * h2f((unsigned short)(w.w >> 16));
        }
        ushort4 q1, q2;
        q1.x = __half_as_ushort(__float2half(a1.x));
        q1.y = __half_as_ushort(__float2half(a1.y));
        q1.z = __half_as_ushort(__float2half(a1.z));
        q1.w = __half_as_ushort(__float2half(a1.w));
        q2.x = __half_as_ushort(__float2half(a2.x));
        q2.y = __half_as_ushort(__float2half(a2.y));
        q2.z = __half_as_ushort(__float2half(a2.z));
        q2.w = __half_as_ushort(__float2half(a2.w));
        // 32-dim-slice layout: xw[s][r][d32], lane's slice = ln>>3.
        size_t idx = (size_t)(ln >> 3) * (N_NODES * 8) + (size_t)r * 8 + (ln & 7);
        xw1s[idx] = q1;
        xw2s[idx] = q2;
    }
}

// -----------------------------------------------------------------------------
// Phase 2, FUSED (measured ~62 us rounds 15-20; request/latency floor, keep):
//   out[r, 32s:32s+32] = relu( sum_adj1 v*xw1[s][c][:] + sum_adj2 v*xw2[s][c][:] )
// -----------------------------------------------------------------------------
__global__ __launch_bounds__(512) void adj_pass_fused(
        const int* __restrict__ starts,
        const int* __restrict__ rowlen,
        const unsigned* __restrict__ spack,
        const ushort4* __restrict__ xw1s,
        const ushort4* __restrict__ xw2s,
        vf4* __restrict__ out) {
    int s  = blockIdx.x & (ADJ_SL - 1);
    int rc = blockIdx.x >> 2;
    int g  = threadIdx.x >> 3;          // 64 row-groups per block
    int q  = threadIdx.x & 7;
    int r  = rc * 64 + g;
    bool valid = (r < N_NODES);
    vf4 acc = {0.f, 0.f, 0.f, 0.f};

#pragma unroll
    for (int rel = 0; rel < 2; ++rel) {
        const ushort4* __restrict__ sl =
            ((rel == 0) ? xw1s : xw2s) + (size_t)s * (N_NODES * 8);
        int st = 0, en = 0;
        if (valid) {
            st = starts[(1 + rel) * N_NODES + r];
            en = st + rowlen[(1 + rel) * N_NODES + r];
        }
        for (int base = st; base < en; base += 16) {
            int m = en - base;
            unsigned pk0 = (q < m)     ? spack[base + q]     : 0u;
            unsigned pk1 = (8 + q < m) ? spack[base + 8 + q] : 0u;
            {
                unsigned pp[8]; ushort4 xx[8];
#pragma unroll
                for (int k = 0; k < 8; ++k) pp[k] = __shfl(pk0, k, 8);
#pragma unroll
                for (int k = 0; k < 8; ++k) xx[k] = sl[upk_c(pp[k]) * 8 + q];
#pragma unroll
                for (int k = 0; k < 8; ++k) {
                    float v = upk_v(pp[k]);
                    acc.x += v * h2f(xx[k].x); acc.y += v * h2f(xx[k].y);
                    acc.z += v * h2f(xx[k].z); acc.w += v * h2f(xx[k].w);
                }
            }
            if (m <= 8) continue;
            {
                unsigned pp[8]; ushort4 xx[8];
#pragma unroll
                for (int k = 0; k < 8; ++k) pp[k] = __shfl(pk1, k, 8);
#pragma unroll
                for (int k = 0; k < 8; ++k) xx[k] = sl[upk_c(pp[k]) * 8 + q];
#pragma unroll
                for (int k = 0; k < 8; ++k) {
                    float v = upk_v(pp[k]);
                    acc.x += v * h2f(xx[k].x); acc.y += v * h2f(xx[k].y);
                    acc.z += v * h2f(xx[k].z); acc.w += v * h2f(xx[k].w);
                }
            }
        }
    }
    if (valid) {
        vf4 res;
        res.x = fmaxf(acc.x, 0.f);
        res.y = fmaxf(acc.y, 0.f);
        res.z = fmaxf(acc.z, 0.f);
        res.w = fmaxf(acc.w, 0.f);
        __builtin_nontemporal_store(res, &out[(size_t)r * 32 + s * 8 + q]);
    }
}

extern "C" void kernel_launch(void* const* d_in, const int* in_sizes, int n_in,
                              void* d_out, int out_size, void* d_ws, size_t ws_size,
                              hipStream_t stream) {
    const int*   feat_row  = (const int*)  d_in[0];
    const int*   feat_col  = (const int*)  d_in[1];
    const float* feat_vals = (const float*)d_in[2];
    const int*   adj1_row  = (const int*)  d_in[3];
    const int*   adj1_col  = (const int*)  d_in[4];
    const float* adj1_vals = (const float*)d_in[5];
    const int*   adj2_row  = (const int*)  d_in[6];
    const int*   adj2_col  = (const int*)  d_in[7];
    const float* adj2_vals = (const float*)d_in[8];
    const float* W1        = (const float*)d_in[9];
    const float* W2        = (const float*)d_in[10];

    // Workspace layout (~62 MB, no aliasing).
    char* ws = (char*)d_ws;
    unsigned* spack = (unsigned*)ws;            ws += (size_t)TOTAL_NNZ * 4;          // 9.6 MB
    int*      starts= (int*)ws;                 ws += (size_t)SCAN_N * 4;             // 600 KB
    int*      rowlen= (int*)ws;                 ws += (size_t)SCAN_N * 4;             // 600 KB
    int*      subcur= (int*)ws;                 ws += 512 * 4;                        // 511 used
    int*      cur3  = (int*)ws;                 ws += 16 * 4;                         // 3 used
    uint4*    Wc    = (uint4*)ws;               ws += (size_t)256 * 32 * 16;          // 128 KB
    unsigned long long* gbuf = (unsigned long long*)ws;
    ws += (size_t)NSB * SUBCAP * 8;                                                  // 25.1 MB
    ushort4*  xw1s  = (ushort4*)ws;             ws += (size_t)N_NODES * OUT_DIM * 2;  // 12.8 MB
    ushort4*  xw2s  = (ushort4*)ws;             ws += (size_t)N_NODES * OUT_DIM * 2;  // 12.8 MB

    // Zero cursors: subcur(512) + cur3(16), contiguous.
    (void)hipMemsetAsync(subcur, 0, (512 + 16) * sizeof(int), stream);

    // W prep: interleaved fp16 table.
    wprep_kernel<<<32, 256, 0, stream>>>(W1, W2, Wc);

    // A: single pass — read all 9 streams once (paired 8B loads), bucket into
    // 511 sub-buckets.
    superbucket_kernel<<<SB_GRID, 512, 0, stream>>>(
        feat_row, feat_col, feat_vals,
        adj1_row, adj1_col, adj1_vals,
        adj2_row, adj2_col, adj2_vals,
        subcur, gbuf);

    // B: sort + adj spack write + FUSED feat xw compute.
    sort_write_feat_kernel<<<NSB, 512, 0, stream>>>(
        gbuf, subcur, cur3, starts, rowlen, spack, Wc, xw1s, xw2s);

    // Phase 2: FUSED rel0+rel1, 32-dim slices.
    adj_pass_fused<<<ADJ_SL * ADJ_RC, 512, 0, stream>>>(
        starts, rowlen, spack, xw1s, xw2s, (vf4*)d_out);
}